// Round 12
// baseline (1181.510 us; speedup 1.0000x reference)
//
#include <hip/hip_runtime.h>
#include <math.h>

#define TT 200
#define BB 16384
#define HH 20
#define EPB 64   // elements per block; grid 256 = 1 block/CU

// s_w layout (f32 element offsets), gate-transposed for v_pk_fma_f32:
// W*pk: [unit][j][gate] ; biases: [unit][gate]
#define OWI0P 0      // 160   W_ih0 pk [20][2][4]
#define OWH0P 160    // 1600  W_hh0 pk [20][20][4]
#define OB0P  1760   // 80    (b_ih0+b_hh0) pk [20][4]
#define OWI1P 1840   // 1600  W_ih1 pk [20][20][4]
#define OWH1P 3440   // 1600  W_hh1 pk [20][20][4]
#define OB1P  5040   // 80    (b_ih1+b_hh1) pk [20][4]
#define SWN   5120

typedef float v2f __attribute__((ext_vector_type(2)));

__device__ double g_bd[3];   // b_dec in f64

// ---------- JAX threefry2x32, key = jax.random.key(42) = [0, 42] ----------
__device__ __forceinline__ void tf2x32(unsigned x0, unsigned x1,
                                       unsigned* o0, unsigned* o1) {
  const unsigned ks0 = 0u, ks1 = 42u;
  const unsigned ks2 = ks0 ^ ks1 ^ 0x1BD11BDAu;
  x0 += ks0; x1 += ks1;
#define ROTL_(v, d) (((v) << (d)) | ((v) >> (32 - (d))))
#define RND_(r) { x0 += x1; x1 = ROTL_(x1, r); x1 ^= x0; }
  RND_(13) RND_(15) RND_(26) RND_(6)
  x0 += ks1; x1 += ks2 + 1u;
  RND_(17) RND_(29) RND_(16) RND_(24)
  x0 += ks2; x1 += ks0 + 2u;
  RND_(13) RND_(15) RND_(26) RND_(6)
  x0 += ks0; x1 += ks1 + 3u;
  RND_(17) RND_(29) RND_(16) RND_(24)
  x0 += ks1; x1 += ks2 + 4u;
  RND_(13) RND_(15) RND_(26) RND_(6)
  x0 += ks2; x1 += ks0 + 5u;
  *o0 = x0; *o1 = x1;
#undef RND_
#undef ROTL_
}

// uniform bits -> gumbel sample (f32 bit manipulation exact; logs in f64)
__device__ __forceinline__ double bits2gumbel(unsigned bits) {
  float f = __uint_as_float((bits >> 9) | 0x3F800000u) - 1.0f;
  float uf = (f > 0.0f) ? f : 1.17549435e-38f;  // max(tiny, f) semantics
  return -log(-log((double)uf));
}

// ---------- f32 activations (HW exp + HW rcp, no clamp / no NR) ----------
__device__ __forceinline__ float sigm_f(float x) {
  float e = __expf(-x);
  return __builtin_amdgcn_rcpf(1.0f + e);
}
__device__ __forceinline__ float tanh_f(float x) {
  float e = __expf(2.0f * x);
  return 1.0f - 2.0f * __builtin_amdgcn_rcpf(1.0f + e);
}

__global__ void prep_kernel(const float* __restrict__ b_dec) {
  int i = threadIdx.x;
  if (i < 3) g_bd[i] = (double)b_dec[i];
}

// layer-0 chunk, 2 elements per lane (r9): each weight ds_read_b128 feeds
// 4 v_pk_fma_f32. Per-gate FMA order: bias, ih j asc, hh j asc.
template <int NC>
__device__ __forceinline__ void l0_chunk(const float* __restrict__ sw, int u0,
                                         float x0a, float x1a,
                                         float x0b, float x1b,
                                         const float* hpA, const float* hpB,
                                         float* cA, float* cB,
                                         float* dstA, float* dstB) {
  v2f a01[NC], a23[NC], b01[NC], b23[NC];
#pragma unroll
  for (int u = 0; u < NC; ++u) {
    float4 b = *(const float4*)&sw[OB0P + (u0 + u) * 4];
    a01[u] = (v2f){b.x, b.y}; a23[u] = (v2f){b.z, b.w};
    b01[u] = (v2f){b.x, b.y}; b23[u] = (v2f){b.z, b.w};
  }
#pragma unroll
  for (int u = 0; u < NC; ++u) {
    float4 wa = *(const float4*)&sw[OWI0P + (u0 + u) * 8 + 0];
    float4 wb = *(const float4*)&sw[OWI0P + (u0 + u) * 8 + 4];
    a01[u] = __builtin_elementwise_fma((v2f){wa.x, wa.y}, (v2f){x0a, x0a}, a01[u]);
    a23[u] = __builtin_elementwise_fma((v2f){wa.z, wa.w}, (v2f){x0a, x0a}, a23[u]);
    b01[u] = __builtin_elementwise_fma((v2f){wa.x, wa.y}, (v2f){x0b, x0b}, b01[u]);
    b23[u] = __builtin_elementwise_fma((v2f){wa.z, wa.w}, (v2f){x0b, x0b}, b23[u]);
    a01[u] = __builtin_elementwise_fma((v2f){wb.x, wb.y}, (v2f){x1a, x1a}, a01[u]);
    a23[u] = __builtin_elementwise_fma((v2f){wb.z, wb.w}, (v2f){x1a, x1a}, a23[u]);
    b01[u] = __builtin_elementwise_fma((v2f){wb.x, wb.y}, (v2f){x1b, x1b}, b01[u]);
    b23[u] = __builtin_elementwise_fma((v2f){wb.z, wb.w}, (v2f){x1b, x1b}, b23[u]);
  }
#pragma unroll
  for (int j = 0; j < HH; ++j) {
    v2f ha = (v2f){hpA[j], hpA[j]};
    v2f hb = (v2f){hpB[j], hpB[j]};
#pragma unroll
    for (int u = 0; u < NC; ++u) {
      float4 w = *(const float4*)&sw[OWH0P + ((u0 + u) * HH + j) * 4];
      a01[u] = __builtin_elementwise_fma((v2f){w.x, w.y}, ha, a01[u]);
      a23[u] = __builtin_elementwise_fma((v2f){w.z, w.w}, ha, a23[u]);
      b01[u] = __builtin_elementwise_fma((v2f){w.x, w.y}, hb, b01[u]);
      b23[u] = __builtin_elementwise_fma((v2f){w.z, w.w}, hb, b23[u]);
    }
  }
#pragma unroll
  for (int u = 0; u < NC; ++u) {
    { float si = sigm_f(a01[u].x), sf = sigm_f(a01[u].y);
      float tg = tanh_f(a23[u].x), so = sigm_f(a23[u].y);
      float c = fmaf(sf, cA[u], si * tg);
      cA[u] = c; dstA[u] = so * tanh_f(c); }
    { float si = sigm_f(b01[u].x), sf = sigm_f(b01[u].y);
      float tg = tanh_f(b23[u].x), so = sigm_f(b23[u].y);
      float c = fmaf(sf, cB[u], si * tg);
      cB[u] = c; dstB[u] = so * tanh_f(c); }
  }
}

// layer-1 chunk, 2 units x 2 elements, LDS weights (r9, unchanged).
__device__ __forceinline__ void l1_chunk2(const float* __restrict__ sw, int u0,
                                          const float* hpA, const float* hpB,
                                          const float* h1A, const float* h1B,
                                          float* cA, float* cB,
                                          float* dstA, float* dstB,
                                          double wd00, double wd01,
                                          double wd10, double wd11,
                                          double wd20, double wd21,
                                          double* lgA, double* lgB) {
  v2f a01[2], a23[2], b01[2], b23[2];
#pragma unroll
  for (int u = 0; u < 2; ++u) {
    float4 b = *(const float4*)&sw[OB1P + (u0 + u) * 4];
    a01[u] = (v2f){b.x, b.y}; a23[u] = (v2f){b.z, b.w};
    b01[u] = (v2f){b.x, b.y}; b23[u] = (v2f){b.z, b.w};
  }
#pragma unroll
  for (int j = 0; j < HH; ++j) {
    v2f ha = (v2f){hpA[j], hpA[j]};
    v2f hb = (v2f){hpB[j], hpB[j]};
#pragma unroll
    for (int u = 0; u < 2; ++u) {
      float4 w = *(const float4*)&sw[OWI1P + ((u0 + u) * HH + j) * 4];
      a01[u] = __builtin_elementwise_fma((v2f){w.x, w.y}, ha, a01[u]);
      a23[u] = __builtin_elementwise_fma((v2f){w.z, w.w}, ha, a23[u]);
      b01[u] = __builtin_elementwise_fma((v2f){w.x, w.y}, hb, b01[u]);
      b23[u] = __builtin_elementwise_fma((v2f){w.z, w.w}, hb, b23[u]);
    }
  }
#pragma unroll
  for (int j = 0; j < HH; ++j) {
    v2f ha = (v2f){h1A[j], h1A[j]};
    v2f hb = (v2f){h1B[j], h1B[j]};
#pragma unroll
    for (int u = 0; u < 2; ++u) {
      float4 w = *(const float4*)&sw[OWH1P + ((u0 + u) * HH + j) * 4];
      a01[u] = __builtin_elementwise_fma((v2f){w.x, w.y}, ha, a01[u]);
      a23[u] = __builtin_elementwise_fma((v2f){w.z, w.w}, ha, a23[u]);
      b01[u] = __builtin_elementwise_fma((v2f){w.x, w.y}, hb, b01[u]);
      b23[u] = __builtin_elementwise_fma((v2f){w.z, w.w}, hb, b23[u]);
    }
  }
#pragma unroll
  for (int u = 0; u < 2; ++u) {
    { float si = sigm_f(a01[u].x), sf = sigm_f(a01[u].y);
      float tg = tanh_f(a23[u].x), so = sigm_f(a23[u].y);
      float c = fmaf(sf, cA[u], si * tg);
      cA[u] = c;
      float h = so * tanh_f(c);
      dstA[u] = h;
      double hd = (double)h;
      if (u == 0) { lgA[0] = fma(wd00, hd, lgA[0]); lgA[1] = fma(wd10, hd, lgA[1]); lgA[2] = fma(wd20, hd, lgA[2]); }
      else        { lgA[0] = fma(wd01, hd, lgA[0]); lgA[1] = fma(wd11, hd, lgA[1]); lgA[2] = fma(wd21, hd, lgA[2]); } }
    { float si = sigm_f(b01[u].x), sf = sigm_f(b01[u].y);
      float tg = tanh_f(b23[u].x), so = sigm_f(b23[u].y);
      float c = fmaf(sf, cB[u], si * tg);
      cB[u] = c;
      float h = so * tanh_f(c);
      dstB[u] = h;
      double hd = (double)h;
      if (u == 0) { lgB[0] = fma(wd00, hd, lgB[0]); lgB[1] = fma(wd10, hd, lgB[1]); lgB[2] = fma(wd20, hd, lgB[2]); }
      else        { lgB[0] = fma(wd01, hd, lgB[0]); lgB[1] = fma(wd11, hd, lgB[1]); lgB[2] = fma(wd21, hd, lgB[2]); } }
  }
}

// layer-1 SMEM quad: 4 units (wave-uniform u0), 1 element per lane.
// Scalar weights via wave-uniform s_load from original row-major arrays
// (r5-proven pattern — register-cheap, no pk/quad s_load batching).
// Per-gate FMA order: bias, ih j asc, hh j asc — identical chains.
__device__ __forceinline__ void l1_quad_smem(
    const float* __restrict__ Wih1, const float* __restrict__ Whh1,
    const float* __restrict__ bih1, const float* __restrict__ bhh1,
    int u0, const float* hp0, const float* h1r, float* c_st, float* dst,
    float4 w0, float4 w1, float4 w2, double* lgA, double* lgB) {
  float acc[4][4];
#pragma unroll
  for (int u = 0; u < 4; ++u)
#pragma unroll
    for (int g = 0; g < 4; ++g) {
      int row = g * 20 + u0 + u;
      acc[u][g] = bih1[row] + bhh1[row];
    }
#pragma unroll
  for (int j = 0; j < HH; ++j) {
    float hj = hp0[j];
#pragma unroll
    for (int u = 0; u < 4; ++u)
#pragma unroll
      for (int g = 0; g < 4; ++g)
        acc[u][g] = fmaf(Wih1[(g * 20 + u0 + u) * HH + j], hj, acc[u][g]);
  }
#pragma unroll
  for (int j = 0; j < HH; ++j) {
    float hj = h1r[j];
#pragma unroll
    for (int u = 0; u < 4; ++u)
#pragma unroll
      for (int g = 0; g < 4; ++g)
        acc[u][g] = fmaf(Whh1[(g * 20 + u0 + u) * HH + j], hj, acc[u][g]);
  }
#pragma unroll
  for (int u = 0; u < 4; ++u) {
    float si = sigm_f(acc[u][0]), sf = sigm_f(acc[u][1]);
    float tg = tanh_f(acc[u][2]), so = sigm_f(acc[u][3]);
    float c = fmaf(sf, c_st[u], si * tg);
    c_st[u] = c;
    float h = so * tanh_f(c);
    dst[u] = h;
    double hd = (double)h;
    double* lg = (u < 2) ? lgA : lgB;
    float f0 = (u == 0) ? w0.x : (u == 1) ? w0.y : (u == 2) ? w0.z : w0.w;
    float f1 = (u == 0) ? w1.x : (u == 1) ? w1.y : (u == 2) ? w1.z : w1.w;
    float f2 = (u == 0) ? w2.x : (u == 1) ? w2.y : (u == 2) ? w2.z : w2.w;
    lg[0] = fma((double)f0, hd, lg[0]);
    lg[1] = fma((double)f1, hd, lg[1]);
    lg[2] = fma((double)f2, hd, lg[2]);
  }
}

// 8 waves / 64 elements / 256 blocks (1 block/CU).
// Waves 0-2 = layer-0 (LDS pk weights, hf-split, 2 elements/lane).
// Waves 3-5 = layer-1 units 0-11 (LDS pk weights, hf-split, 2 elems/lane).
// Waves 6-7 = layer-1 units 12-19 (scalar SMEM weights, lane=element,
//   4 units/wave, wave-uniform) — moves ~26% of weight traffic off the
//   saturated LDS pipe onto the idle SMEM/K$ pipe.
__global__ __launch_bounds__(512, 2) void lstm_wave_kernel(
    const float* __restrict__ x,      // [T,B,2]
    const float* __restrict__ h0_in,  // [2,B,20]
    const float* __restrict__ c0_in,  // [2,B,20]
    const float* __restrict__ Wih0,   // [80,2]
    const float* __restrict__ Whh0,   // [80,20]
    const float* __restrict__ bih0,   // [80]
    const float* __restrict__ bhh0,   // [80]
    const float* __restrict__ Wih1,   // [80,20]
    const float* __restrict__ Whh1,   // [80,20]
    const float* __restrict__ bih1,   // [80]
    const float* __restrict__ bhh1,   // [80]
    const float* __restrict__ Wdec_f, // [3,4000]
    float* __restrict__ out) {
  __shared__ float s_h0[2][EPB][22];   // stride 22 dwords
  __shared__ float s_h1[2][EPB][22];
  __shared__ double s_logit[10][EPB][3];
  __shared__ __align__(16) float s_w[SWN];  // gate-transposed weights

  const int tid = threadIdx.x;
  const int lane = tid & 63;
  const int wv = __builtin_amdgcn_readfirstlane((int)(tid >> 6));
  const int e = lane & 31;
  const int hf = lane >> 5;
  const int eg0 = blockIdx.x * EPB + e;
  const int eg1 = eg0 + 32;
  const int el = lane;                     // SMEM-wave path: lane = element
  const int egl = blockIdx.x * EPB + el;

  // stage gate-transposed weights/biases into LDS (one-time)
  for (int i = tid; i < SWN; i += 512) {
    float v;
    if (i < OWH0P) {                     // ih0: i = (u*2+j)*4+g
      int g = i & 3, t = i >> 2, j = t & 1, u = t >> 1;
      v = Wih0[(g * 20 + u) * 2 + j];
    } else if (i < OB0P) {               // hh0: k = (u*20+j)*4+g
      int k = i - OWH0P, g = k & 3, t = k >> 2, j = t % 20, u = t / 20;
      v = Whh0[(g * 20 + u) * 20 + j];
    } else if (i < OWI1P) {              // b0: k = u*4+g
      int k = i - OB0P, g = k & 3, u = k >> 2;
      v = bih0[g * 20 + u] + bhh0[g * 20 + u];
    } else if (i < OWH1P) {              // ih1
      int k = i - OWI1P, g = k & 3, t = k >> 2, j = t % 20, u = t / 20;
      v = Wih1[(g * 20 + u) * 20 + j];
    } else if (i < OB1P) {               // hh1
      int k = i - OWH1P, g = k & 3, t = k >> 2, j = t % 20, u = t / 20;
      v = Whh1[(g * 20 + u) * 20 + j];
    } else {                             // b1
      int k = i - OB1P, g = k & 3, u = k >> 2;
      v = bih1[g * 20 + u] + bhh1[g * 20 + u];
    }
    s_w[i] = v;
  }

  const bool isL0 = (wv < 3);
  const bool isSm = (wv >= 6);
  int u0, nu;
  if (isL0) {
    if (wv == 0) { u0 = hf * 4;                    nu = 4; }  // per-lane
    else         { u0 = 8 + (wv - 1) * 6 + hf * 3; nu = 3; }  // per-lane
  } else if (!isSm) {
    u0 = (wv - 3) * 4 + hf * 2; nu = 2;                       // per-lane
  } else {
    u0 = __builtin_amdgcn_readfirstlane(12 + (wv - 6) * 4); nu = 4;  // uniform
  }

  float cA[4], cB[4];
  double lgA[3] = {0.0, 0.0, 0.0};
  double lgB[3] = {0.0, 0.0, 0.0};

  // init: h(-1) into buffer 1 (phases 0/1 read it there)
  if (isL0) {
#pragma unroll
    for (int u = 0; u < 4; ++u) {
      if (u < nu) {
        cA[u] = c0_in[eg0 * HH + u0 + u];
        cB[u] = c0_in[eg1 * HH + u0 + u];
        s_h0[1][e][u0 + u] = h0_in[eg0 * HH + u0 + u];
        s_h0[1][e + 32][u0 + u] = h0_in[eg1 * HH + u0 + u];
      }
    }
  } else if (!isSm) {
#pragma unroll
    for (int u = 0; u < 2; ++u) {
      cA[u] = c0_in[BB * HH + eg0 * HH + u0 + u];
      cB[u] = c0_in[BB * HH + eg1 * HH + u0 + u];
      s_h1[1][e][u0 + u] = h0_in[BB * HH + eg0 * HH + u0 + u];
      s_h1[1][e + 32][u0 + u] = h0_in[BB * HH + eg1 * HH + u0 + u];
    }
  } else {
#pragma unroll
    for (int u = 0; u < 4; ++u) {
      cA[u] = c0_in[BB * HH + egl * HH + u0 + u];
      s_h1[1][el][u0 + u] = h0_in[BB * HH + egl * HH + u0 + u];
    }
  }
  __syncthreads();

  const float2* x2 = (const float2*)x;
  const float2* wd2 = (const float2*)Wdec_f;
  const float4* wdq = (const float4*)Wdec_f;

  // x prefetch registers: hold x(t) one full phase ahead (L0 only).
  float2 xvA_cur, xvB_cur;
  if (isL0) { xvA_cur = x2[0 * BB + eg0]; xvB_cur = x2[0 * BB + eg1]; }

  // phase s: L0 computes t=s (s<200): reads h0 buf (s+1)&1, writes s&1.
  //          L1 computes t1=s-1 (s>=1): h0(t1) from t1&1, own h1(t1-1) from
  //          (t1+1)&1, writes h1(t1) -> t1&1.
  for (int s = 0; s <= TT; ++s) {
    if (isL0) {
      if (s < TT) {
        const int rb = (s + 1) & 1;
        const int wb = s & 1;
        float2 xvA = xvA_cur, xvB = xvB_cur;
        if (s + 1 < TT) {
          xvA_cur = x2[(s + 1) * BB + eg0];
          xvB_cur = x2[(s + 1) * BB + eg1];
        }
        float hpA[HH], hpB[HH];
#pragma unroll
        for (int j2 = 0; j2 < 10; ++j2) {
          float2 vA = *(const float2*)&s_h0[rb][e][2 * j2];
          float2 vB = *(const float2*)&s_h0[rb][e + 32][2 * j2];
          hpA[2 * j2] = vA.x; hpA[2 * j2 + 1] = vA.y;
          hpB[2 * j2] = vB.x; hpB[2 * j2 + 1] = vB.y;
        }
        float* dstA = &s_h0[wb][e][u0];
        float* dstB = &s_h0[wb][e + 32][u0];
        if (wv == 0) l0_chunk<4>(s_w, u0, xvA.x, xvA.y, xvB.x, xvB.y, hpA, hpB, cA, cB, dstA, dstB);
        else         l0_chunk<3>(s_w, u0, xvA.x, xvA.y, xvB.x, xvB.y, hpA, hpB, cA, cB, dstA, dstB);
      }
    } else if (!isSm) {
      if (s >= 1) {
        const int t1 = s - 1;
        const int h0b = t1 & 1;
        const int h1rb = (t1 + 1) & 1;
        const int col = t1 * HH + u0;  // u0 even -> float2 aligned
        float2 w0 = wd2[(0    + col) >> 1];
        float2 w1 = wd2[(4000 + col) >> 1];
        float2 w2 = wd2[(8000 + col) >> 1];
        float hpA[HH], hpB[HH], h1A[HH], h1B[HH];
#pragma unroll
        for (int j2 = 0; j2 < 10; ++j2) {
          float2 vA = *(const float2*)&s_h0[h0b][e][2 * j2];
          float2 vB = *(const float2*)&s_h0[h0b][e + 32][2 * j2];
          hpA[2 * j2] = vA.x; hpA[2 * j2 + 1] = vA.y;
          hpB[2 * j2] = vB.x; hpB[2 * j2 + 1] = vB.y;
          float2 uA = *(const float2*)&s_h1[h1rb][e][2 * j2];
          float2 uB = *(const float2*)&s_h1[h1rb][e + 32][2 * j2];
          h1A[2 * j2] = uA.x; h1A[2 * j2 + 1] = uA.y;
          h1B[2 * j2] = uB.x; h1B[2 * j2 + 1] = uB.y;
        }
        float* dstA = &s_h1[h0b][e][u0];
        float* dstB = &s_h1[h0b][e + 32][u0];
        l1_chunk2(s_w, u0, hpA, hpB, h1A, h1B, cA, cB, dstA, dstB,
                  (double)w0.x, (double)w0.y,
                  (double)w1.x, (double)w1.y,
                  (double)w2.x, (double)w2.y, lgA, lgB);
      }
    } else {
      if (s >= 1) {
        const int t1 = s - 1;
        const int h0b = t1 & 1;
        const int h1rb = (t1 + 1) & 1;
        const int col = t1 * HH + u0;  // u0 in {12,16}, 20|4 -> float4 aligned
        float4 w0 = wdq[(0    + col) >> 2];
        float4 w1 = wdq[(4000 + col) >> 2];
        float4 w2 = wdq[(8000 + col) >> 2];
        float hp0[HH], h1r[HH];
#pragma unroll
        for (int j2 = 0; j2 < 10; ++j2) {
          float2 vA = *(const float2*)&s_h0[h0b][el][2 * j2];
          float2 uA = *(const float2*)&s_h1[h1rb][el][2 * j2];
          hp0[2 * j2] = vA.x; hp0[2 * j2 + 1] = vA.y;
          h1r[2 * j2] = uA.x; h1r[2 * j2 + 1] = uA.y;
        }
        float* dst = &s_h1[h0b][el][u0];
        l1_quad_smem(Wih1, Whh1, bih1, bhh1, u0, hp0, h1r, cA, dst,
                     w0, w1, w2, lgA, lgB);
      }
    }
    __syncthreads();
  }

  // final states: h(199) in buffer 1 (199&1==1)
  if (isL0) {
#pragma unroll
    for (int u = 0; u < 4; ++u) {
      if (u < nu) {
        out[2 * BB + eg0 * HH + u0 + u] = s_h0[1][e][u0 + u];
        out[2 * BB + eg1 * HH + u0 + u] = s_h0[1][e + 32][u0 + u];
        out[2 * BB + 2 * BB * HH + eg0 * HH + u0 + u] = cA[u];
        out[2 * BB + 2 * BB * HH + eg1 * HH + u0 + u] = cB[u];
      }
    }
  } else if (!isSm) {
#pragma unroll
    for (int u = 0; u < 2; ++u) {
      out[2 * BB + BB * HH + eg0 * HH + u0 + u] = s_h1[1][e][u0 + u];
      out[2 * BB + BB * HH + eg1 * HH + u0 + u] = s_h1[1][e + 32][u0 + u];
      out[2 * BB + 2 * BB * HH + BB * HH + eg0 * HH + u0 + u] = cA[u];
      out[2 * BB + 2 * BB * HH + BB * HH + eg1 * HH + u0 + u] = cB[u];
    }
    const int k = (wv - 3) * 2 + hf;  // units 2k,2k+1 (0..11)
    s_logit[k][e][0] = lgA[0];
    s_logit[k][e][1] = lgA[1];
    s_logit[k][e][2] = lgA[2];
    s_logit[k][e + 32][0] = lgB[0];
    s_logit[k][e + 32][1] = lgB[1];
    s_logit[k][e + 32][2] = lgB[2];
  } else {
#pragma unroll
    for (int u = 0; u < 4; ++u) {
      out[2 * BB + BB * HH + egl * HH + u0 + u] = s_h1[1][el][u0 + u];
      out[2 * BB + 2 * BB * HH + BB * HH + egl * HH + u0 + u] = cA[u];
    }
    const int k0 = 6 + (wv - 6) * 2;  // units 12-13 -> 6, ..., 18-19 -> 9
    s_logit[k0][el][0] = lgA[0];
    s_logit[k0][el][1] = lgA[1];
    s_logit[k0][el][2] = lgA[2];
    s_logit[k0 + 1][el][0] = lgB[0];
    s_logit[k0 + 1][el][1] = lgB[1];
    s_logit[k0 + 1][el][2] = lgB[2];
  }
  __syncthreads();

  if (wv == 0) {
    const int ed = lane;                 // 64 lanes, one element each
    const int egd = blockIdx.x * EPB + ed;
    double l[3];
#pragma unroll
    for (int a = 0; a < 3; ++a) {
      double v = g_bd[a];
#pragma unroll
      for (int k = 0; k < 10; ++k) v += s_logit[k][ed][a];
      l[a] = v;
    }

    // partitionable 32-bit stream: hi^lo of threefry2x32(key, (0, flat_idx))
    int act = 0;
    double vbest = -1.0e300;
#pragma unroll
    for (int a = 0; a < 3; ++a) {
      unsigned idx = 3u * (unsigned)egd + (unsigned)a;
      unsigned p0, p1;
      tf2x32(0u, idx, &p0, &p1);
      double g = bits2gumbel(p0 ^ p1);
      double v = l[a] + g;
      if (v > vbest) { vbest = v; act = a; }  // strict >: first max (argmax)
    }
    double m = fmax(l[0], fmax(l[1], l[2]));
    double se = exp(l[0] - m) + exp(l[1] - m) + exp(l[2] - m);
    double lp = (l[act] - m) - log(se);
    out[egd] = (float)act;
    out[BB + egd] = (float)lp;
  }
}

extern "C" void kernel_launch(void* const* d_in, const int* in_sizes, int n_in,
                              void* d_out, int out_size, void* d_ws, size_t ws_size,
                              hipStream_t stream) {
  prep_kernel<<<dim3(1), dim3(64), 0, stream>>>((const float*)d_in[12]);
  lstm_wave_kernel<<<dim3(BB / EPB), dim3(512), 0, stream>>>(
      (const float*)d_in[0], (const float*)d_in[1], (const float*)d_in[2],
      (const float*)d_in[3], (const float*)d_in[4],
      (const float*)d_in[5], (const float*)d_in[6],
      (const float*)d_in[7], (const float*)d_in[8],
      (const float*)d_in[9], (const float*)d_in[10],
      (const float*)d_in[11], (float*)d_out);
}

// Round 13
// 1049.867 us; speedup vs baseline: 1.1254x; 1.1254x over previous
//
#include <hip/hip_runtime.h>
#include <math.h>

#define TT 200
#define BB 16384
#define HH 20
#define EPB 64   // elements per block; grid 256 = 1 block/CU

// s_w layout (f32 element offsets), gate-transposed for v_pk_fma_f32:
// W*pk: [unit][j][gate] ; biases: [unit][gate]
#define OWI0P 0      // 160   W_ih0 pk [20][2][4]
#define OWH0P 160    // 1600  W_hh0 pk [20][20][4]
#define OB0P  1760   // 80    (b_ih0+b_hh0) pk [20][4]
#define OWI1P 1840   // 1600  W_ih1 pk [20][20][4]
#define OWH1P 3440   // 1600  W_hh1 pk [20][20][4]
#define OB1P  5040   // 80    (b_ih1+b_hh1) pk [20][4]
#define SWN   5120

typedef float v2f __attribute__((ext_vector_type(2)));

__device__ double g_bd[3];   // b_dec in f64

// ---------- JAX threefry2x32, key = jax.random.key(42) = [0, 42] ----------
__device__ __forceinline__ void tf2x32(unsigned x0, unsigned x1,
                                       unsigned* o0, unsigned* o1) {
  const unsigned ks0 = 0u, ks1 = 42u;
  const unsigned ks2 = ks0 ^ ks1 ^ 0x1BD11BDAu;
  x0 += ks0; x1 += ks1;
#define ROTL_(v, d) (((v) << (d)) | ((v) >> (32 - (d))))
#define RND_(r) { x0 += x1; x1 = ROTL_(x1, r); x1 ^= x0; }
  RND_(13) RND_(15) RND_(26) RND_(6)
  x0 += ks1; x1 += ks2 + 1u;
  RND_(17) RND_(29) RND_(16) RND_(24)
  x0 += ks2; x1 += ks0 + 2u;
  RND_(13) RND_(15) RND_(26) RND_(6)
  x0 += ks0; x1 += ks1 + 3u;
  RND_(17) RND_(29) RND_(16) RND_(24)
  x0 += ks1; x1 += ks2 + 4u;
  RND_(13) RND_(15) RND_(26) RND_(6)
  x0 += ks2; x1 += ks0 + 5u;
  *o0 = x0; *o1 = x1;
#undef RND_
#undef ROTL_
}

// uniform bits -> gumbel sample (f32 bit manipulation exact; logs in f64)
__device__ __forceinline__ double bits2gumbel(unsigned bits) {
  float f = __uint_as_float((bits >> 9) | 0x3F800000u) - 1.0f;
  float uf = (f > 0.0f) ? f : 1.17549435e-38f;  // max(tiny, f) semantics
  return -log(-log((double)uf));
}

// ---------- f32 activations (HW exp + HW rcp, no clamp / no NR) ----------
__device__ __forceinline__ float sigm_f(float x) {
  float e = __expf(-x);
  return __builtin_amdgcn_rcpf(1.0f + e);
}
__device__ __forceinline__ float tanh_f(float x) {
  float e = __expf(2.0f * x);
  return 1.0f - 2.0f * __builtin_amdgcn_rcpf(1.0f + e);
}

__global__ void prep_kernel(const float* __restrict__ b_dec) {
  int i = threadIdx.x;
  if (i < 3) g_bd[i] = (double)b_dec[i];
}

// layer-0 chunk, 2 elements per lane (r9): each weight ds_read_b128 feeds
// 4 v_pk_fma_f32. Per-gate FMA order: bias, ih j asc, hh j asc.
template <int NC>
__device__ __forceinline__ void l0_chunk(const float* __restrict__ sw, int u0,
                                         float x0a, float x1a,
                                         float x0b, float x1b,
                                         const float* hpA, const float* hpB,
                                         float* cA, float* cB,
                                         float* dstA, float* dstB) {
  v2f a01[NC], a23[NC], b01[NC], b23[NC];
#pragma unroll
  for (int u = 0; u < NC; ++u) {
    float4 b = *(const float4*)&sw[OB0P + (u0 + u) * 4];
    a01[u] = (v2f){b.x, b.y}; a23[u] = (v2f){b.z, b.w};
    b01[u] = (v2f){b.x, b.y}; b23[u] = (v2f){b.z, b.w};
  }
#pragma unroll
  for (int u = 0; u < NC; ++u) {
    float4 wa = *(const float4*)&sw[OWI0P + (u0 + u) * 8 + 0];
    float4 wb = *(const float4*)&sw[OWI0P + (u0 + u) * 8 + 4];
    a01[u] = __builtin_elementwise_fma((v2f){wa.x, wa.y}, (v2f){x0a, x0a}, a01[u]);
    a23[u] = __builtin_elementwise_fma((v2f){wa.z, wa.w}, (v2f){x0a, x0a}, a23[u]);
    b01[u] = __builtin_elementwise_fma((v2f){wa.x, wa.y}, (v2f){x0b, x0b}, b01[u]);
    b23[u] = __builtin_elementwise_fma((v2f){wa.z, wa.w}, (v2f){x0b, x0b}, b23[u]);
    a01[u] = __builtin_elementwise_fma((v2f){wb.x, wb.y}, (v2f){x1a, x1a}, a01[u]);
    a23[u] = __builtin_elementwise_fma((v2f){wb.z, wb.w}, (v2f){x1a, x1a}, a23[u]);
    b01[u] = __builtin_elementwise_fma((v2f){wb.x, wb.y}, (v2f){x1b, x1b}, b01[u]);
    b23[u] = __builtin_elementwise_fma((v2f){wb.z, wb.w}, (v2f){x1b, x1b}, b23[u]);
  }
#pragma unroll
  for (int j = 0; j < HH; ++j) {
    v2f ha = (v2f){hpA[j], hpA[j]};
    v2f hb = (v2f){hpB[j], hpB[j]};
#pragma unroll
    for (int u = 0; u < NC; ++u) {
      float4 w = *(const float4*)&sw[OWH0P + ((u0 + u) * HH + j) * 4];
      a01[u] = __builtin_elementwise_fma((v2f){w.x, w.y}, ha, a01[u]);
      a23[u] = __builtin_elementwise_fma((v2f){w.z, w.w}, ha, a23[u]);
      b01[u] = __builtin_elementwise_fma((v2f){w.x, w.y}, hb, b01[u]);
      b23[u] = __builtin_elementwise_fma((v2f){w.z, w.w}, hb, b23[u]);
    }
  }
#pragma unroll
  for (int u = 0; u < NC; ++u) {
    { float si = sigm_f(a01[u].x), sf = sigm_f(a01[u].y);
      float tg = tanh_f(a23[u].x), so = sigm_f(a23[u].y);
      float c = fmaf(sf, cA[u], si * tg);
      cA[u] = c; dstA[u] = so * tanh_f(c); }
    { float si = sigm_f(b01[u].x), sf = sigm_f(b01[u].y);
      float tg = tanh_f(b23[u].x), so = sigm_f(b23[u].y);
      float c = fmaf(sf, cB[u], si * tg);
      cB[u] = c; dstB[u] = so * tanh_f(c); }
  }
}

// layer-1 chunk, 2 units x 2 elements, LDS weights (r9, unchanged).
__device__ __forceinline__ void l1_chunk2(const float* __restrict__ sw, int u0,
                                          const float* hpA, const float* hpB,
                                          const float* h1A, const float* h1B,
                                          float* cA, float* cB,
                                          float* dstA, float* dstB,
                                          double wd00, double wd01,
                                          double wd10, double wd11,
                                          double wd20, double wd21,
                                          double* lgA, double* lgB) {
  v2f a01[2], a23[2], b01[2], b23[2];
#pragma unroll
  for (int u = 0; u < 2; ++u) {
    float4 b = *(const float4*)&sw[OB1P + (u0 + u) * 4];
    a01[u] = (v2f){b.x, b.y}; a23[u] = (v2f){b.z, b.w};
    b01[u] = (v2f){b.x, b.y}; b23[u] = (v2f){b.z, b.w};
  }
#pragma unroll
  for (int j = 0; j < HH; ++j) {
    v2f ha = (v2f){hpA[j], hpA[j]};
    v2f hb = (v2f){hpB[j], hpB[j]};
#pragma unroll
    for (int u = 0; u < 2; ++u) {
      float4 w = *(const float4*)&sw[OWI1P + ((u0 + u) * HH + j) * 4];
      a01[u] = __builtin_elementwise_fma((v2f){w.x, w.y}, ha, a01[u]);
      a23[u] = __builtin_elementwise_fma((v2f){w.z, w.w}, ha, a23[u]);
      b01[u] = __builtin_elementwise_fma((v2f){w.x, w.y}, hb, b01[u]);
      b23[u] = __builtin_elementwise_fma((v2f){w.z, w.w}, hb, b23[u]);
    }
  }
#pragma unroll
  for (int j = 0; j < HH; ++j) {
    v2f ha = (v2f){h1A[j], h1A[j]};
    v2f hb = (v2f){h1B[j], h1B[j]};
#pragma unroll
    for (int u = 0; u < 2; ++u) {
      float4 w = *(const float4*)&sw[OWH1P + ((u0 + u) * HH + j) * 4];
      a01[u] = __builtin_elementwise_fma((v2f){w.x, w.y}, ha, a01[u]);
      a23[u] = __builtin_elementwise_fma((v2f){w.z, w.w}, ha, a23[u]);
      b01[u] = __builtin_elementwise_fma((v2f){w.x, w.y}, hb, b01[u]);
      b23[u] = __builtin_elementwise_fma((v2f){w.z, w.w}, hb, b23[u]);
    }
  }
#pragma unroll
  for (int u = 0; u < 2; ++u) {
    { float si = sigm_f(a01[u].x), sf = sigm_f(a01[u].y);
      float tg = tanh_f(a23[u].x), so = sigm_f(a23[u].y);
      float c = fmaf(sf, cA[u], si * tg);
      cA[u] = c;
      float h = so * tanh_f(c);
      dstA[u] = h;
      double hd = (double)h;
      if (u == 0) { lgA[0] = fma(wd00, hd, lgA[0]); lgA[1] = fma(wd10, hd, lgA[1]); lgA[2] = fma(wd20, hd, lgA[2]); }
      else        { lgA[0] = fma(wd01, hd, lgA[0]); lgA[1] = fma(wd11, hd, lgA[1]); lgA[2] = fma(wd21, hd, lgA[2]); } }
    { float si = sigm_f(b01[u].x), sf = sigm_f(b01[u].y);
      float tg = tanh_f(b23[u].x), so = sigm_f(b23[u].y);
      float c = fmaf(sf, cB[u], si * tg);
      cB[u] = c;
      float h = so * tanh_f(c);
      dstB[u] = h;
      double hd = (double)h;
      if (u == 0) { lgB[0] = fma(wd00, hd, lgB[0]); lgB[1] = fma(wd10, hd, lgB[1]); lgB[2] = fma(wd20, hd, lgB[2]); }
      else        { lgB[0] = fma(wd01, hd, lgB[0]); lgB[1] = fma(wd11, hd, lgB[1]); lgB[2] = fma(wd21, hd, lgB[2]); } }
  }
}

// layer-1 SMEM pair: 2 units (wave-uniform u0), 1 element per lane.
// Scalar weights via wave-uniform s_load from original row-major arrays.
// r5-proven chunk size (<=160-dword unrolled s_load window) — the r10/r12
// 4-unit quads overflowed the s_load batch window and spilled.
// Per-gate FMA order: bias, ih j asc, hh j asc — identical chains.
__device__ __forceinline__ void l1_smem2(
    const float* __restrict__ Wih1, const float* __restrict__ Whh1,
    const float* __restrict__ bih1, const float* __restrict__ bhh1,
    int u0, const float* hp0, const float* h1r, float* c_st, float* dst,
    float2 w0, float2 w1, float2 w2, double* lg) {
  float acc[2][4];
#pragma unroll
  for (int u = 0; u < 2; ++u)
#pragma unroll
    for (int g = 0; g < 4; ++g) {
      int row = g * 20 + u0 + u;
      acc[u][g] = bih1[row] + bhh1[row];
    }
#pragma unroll
  for (int j = 0; j < HH; ++j) {
    float hj = hp0[j];
#pragma unroll
    for (int u = 0; u < 2; ++u)
#pragma unroll
      for (int g = 0; g < 4; ++g)
        acc[u][g] = fmaf(Wih1[(g * 20 + u0 + u) * HH + j], hj, acc[u][g]);
  }
#pragma unroll
  for (int j = 0; j < HH; ++j) {
    float hj = h1r[j];
#pragma unroll
    for (int u = 0; u < 2; ++u)
#pragma unroll
      for (int g = 0; g < 4; ++g)
        acc[u][g] = fmaf(Whh1[(g * 20 + u0 + u) * HH + j], hj, acc[u][g]);
  }
#pragma unroll
  for (int u = 0; u < 2; ++u) {
    float si = sigm_f(acc[u][0]), sf = sigm_f(acc[u][1]);
    float tg = tanh_f(acc[u][2]), so = sigm_f(acc[u][3]);
    float c = fmaf(sf, c_st[u], si * tg);
    c_st[u] = c;
    float h = so * tanh_f(c);
    dst[u] = h;
    double hd = (double)h;
    float f0 = (u == 0) ? w0.x : w0.y;
    float f1 = (u == 0) ? w1.x : w1.y;
    float f2 = (u == 0) ? w2.x : w2.y;
    lg[0] = fma((double)f0, hd, lg[0]);
    lg[1] = fma((double)f1, hd, lg[1]);
    lg[2] = fma((double)f2, hd, lg[2]);
  }
}

// 8 waves / 64 elements / 256 blocks (1 block/CU).
// Waves 0-2 = layer-0 (LDS pk weights, hf-split, 2 elements/lane).
// Waves 3-5 = layer-1 units 0-11 (LDS pk weights, hf-split, 2 elems/lane).
// Waves 6-7 = layer-1 units 12-19 (scalar SMEM weights, lane=element,
//   wave-uniform u0, TWO sequential 2-unit chunks) — moves ~26% of weight
//   traffic off the LDS pipe onto the idle SMEM/K$ pipe, r5-safe chunking.
__global__ __launch_bounds__(512, 2) void lstm_wave_kernel(
    const float* __restrict__ x,      // [T,B,2]
    const float* __restrict__ h0_in,  // [2,B,20]
    const float* __restrict__ c0_in,  // [2,B,20]
    const float* __restrict__ Wih0,   // [80,2]
    const float* __restrict__ Whh0,   // [80,20]
    const float* __restrict__ bih0,   // [80]
    const float* __restrict__ bhh0,   // [80]
    const float* __restrict__ Wih1,   // [80,20]
    const float* __restrict__ Whh1,   // [80,20]
    const float* __restrict__ bih1,   // [80]
    const float* __restrict__ bhh1,   // [80]
    const float* __restrict__ Wdec_f, // [3,4000]
    float* __restrict__ out) {
  __shared__ float s_h0[2][EPB][22];   // stride 22 dwords
  __shared__ float s_h1[2][EPB][22];
  __shared__ double s_logit[10][EPB][3];
  __shared__ __align__(16) float s_w[SWN];  // gate-transposed weights

  const int tid = threadIdx.x;
  const int lane = tid & 63;
  const int wv = __builtin_amdgcn_readfirstlane((int)(tid >> 6));
  const int e = lane & 31;
  const int hf = lane >> 5;
  const int eg0 = blockIdx.x * EPB + e;
  const int eg1 = eg0 + 32;
  const int el = lane;                     // SMEM-wave path: lane = element
  const int egl = blockIdx.x * EPB + el;

  // stage gate-transposed weights/biases into LDS (one-time)
  for (int i = tid; i < SWN; i += 512) {
    float v;
    if (i < OWH0P) {                     // ih0: i = (u*2+j)*4+g
      int g = i & 3, t = i >> 2, j = t & 1, u = t >> 1;
      v = Wih0[(g * 20 + u) * 2 + j];
    } else if (i < OB0P) {               // hh0: k = (u*20+j)*4+g
      int k = i - OWH0P, g = k & 3, t = k >> 2, j = t % 20, u = t / 20;
      v = Whh0[(g * 20 + u) * 20 + j];
    } else if (i < OWI1P) {              // b0: k = u*4+g
      int k = i - OB0P, g = k & 3, u = k >> 2;
      v = bih0[g * 20 + u] + bhh0[g * 20 + u];
    } else if (i < OWH1P) {              // ih1
      int k = i - OWI1P, g = k & 3, t = k >> 2, j = t % 20, u = t / 20;
      v = Wih1[(g * 20 + u) * 20 + j];
    } else if (i < OB1P) {               // hh1
      int k = i - OWH1P, g = k & 3, t = k >> 2, j = t % 20, u = t / 20;
      v = Whh1[(g * 20 + u) * 20 + j];
    } else {                             // b1
      int k = i - OB1P, g = k & 3, u = k >> 2;
      v = bih1[g * 20 + u] + bhh1[g * 20 + u];
    }
    s_w[i] = v;
  }

  const bool isL0 = (wv < 3);
  const bool isSm = (wv >= 6);
  int u0, nu;
  if (isL0) {
    if (wv == 0) { u0 = hf * 4;                    nu = 4; }  // per-lane
    else         { u0 = 8 + (wv - 1) * 6 + hf * 3; nu = 3; }  // per-lane
  } else if (!isSm) {
    u0 = (wv - 3) * 4 + hf * 2; nu = 2;                       // per-lane
  } else {
    u0 = __builtin_amdgcn_readfirstlane(12 + (wv - 6) * 4); nu = 4;  // uniform
  }

  float cA[4], cB[4];
  double lgA[3] = {0.0, 0.0, 0.0};
  double lgB[3] = {0.0, 0.0, 0.0};

  // init: h(-1) into buffer 1 (phases 0/1 read it there)
  if (isL0) {
#pragma unroll
    for (int u = 0; u < 4; ++u) {
      if (u < nu) {
        cA[u] = c0_in[eg0 * HH + u0 + u];
        cB[u] = c0_in[eg1 * HH + u0 + u];
        s_h0[1][e][u0 + u] = h0_in[eg0 * HH + u0 + u];
        s_h0[1][e + 32][u0 + u] = h0_in[eg1 * HH + u0 + u];
      }
    }
  } else if (!isSm) {
#pragma unroll
    for (int u = 0; u < 2; ++u) {
      cA[u] = c0_in[BB * HH + eg0 * HH + u0 + u];
      cB[u] = c0_in[BB * HH + eg1 * HH + u0 + u];
      s_h1[1][e][u0 + u] = h0_in[BB * HH + eg0 * HH + u0 + u];
      s_h1[1][e + 32][u0 + u] = h0_in[BB * HH + eg1 * HH + u0 + u];
    }
  } else {
#pragma unroll
    for (int u = 0; u < 4; ++u) {
      cA[u] = c0_in[BB * HH + egl * HH + u0 + u];
      s_h1[1][el][u0 + u] = h0_in[BB * HH + egl * HH + u0 + u];
    }
  }
  __syncthreads();

  const float2* x2 = (const float2*)x;
  const float2* wd2 = (const float2*)Wdec_f;

  // x prefetch registers: hold x(t) one full phase ahead (L0 only).
  float2 xvA_cur, xvB_cur;
  if (isL0) { xvA_cur = x2[0 * BB + eg0]; xvB_cur = x2[0 * BB + eg1]; }

  // phase s: L0 computes t=s (s<200): reads h0 buf (s+1)&1, writes s&1.
  //          L1 computes t1=s-1 (s>=1): h0(t1) from t1&1, own h1(t1-1) from
  //          (t1+1)&1, writes h1(t1) -> t1&1.
  for (int s = 0; s <= TT; ++s) {
    if (isL0) {
      if (s < TT) {
        const int rb = (s + 1) & 1;
        const int wb = s & 1;
        float2 xvA = xvA_cur, xvB = xvB_cur;
        if (s + 1 < TT) {
          xvA_cur = x2[(s + 1) * BB + eg0];
          xvB_cur = x2[(s + 1) * BB + eg1];
        }
        float hpA[HH], hpB[HH];
#pragma unroll
        for (int j2 = 0; j2 < 10; ++j2) {
          float2 vA = *(const float2*)&s_h0[rb][e][2 * j2];
          float2 vB = *(const float2*)&s_h0[rb][e + 32][2 * j2];
          hpA[2 * j2] = vA.x; hpA[2 * j2 + 1] = vA.y;
          hpB[2 * j2] = vB.x; hpB[2 * j2 + 1] = vB.y;
        }
        float* dstA = &s_h0[wb][e][u0];
        float* dstB = &s_h0[wb][e + 32][u0];
        if (wv == 0) l0_chunk<4>(s_w, u0, xvA.x, xvA.y, xvB.x, xvB.y, hpA, hpB, cA, cB, dstA, dstB);
        else         l0_chunk<3>(s_w, u0, xvA.x, xvA.y, xvB.x, xvB.y, hpA, hpB, cA, cB, dstA, dstB);
      }
    } else if (!isSm) {
      if (s >= 1) {
        const int t1 = s - 1;
        const int h0b = t1 & 1;
        const int h1rb = (t1 + 1) & 1;
        const int col = t1 * HH + u0;  // u0 even -> float2 aligned
        float2 w0 = wd2[(0    + col) >> 1];
        float2 w1 = wd2[(4000 + col) >> 1];
        float2 w2 = wd2[(8000 + col) >> 1];
        float hpA[HH], hpB[HH], h1A[HH], h1B[HH];
#pragma unroll
        for (int j2 = 0; j2 < 10; ++j2) {
          float2 vA = *(const float2*)&s_h0[h0b][e][2 * j2];
          float2 vB = *(const float2*)&s_h0[h0b][e + 32][2 * j2];
          hpA[2 * j2] = vA.x; hpA[2 * j2 + 1] = vA.y;
          hpB[2 * j2] = vB.x; hpB[2 * j2 + 1] = vB.y;
          float2 uA = *(const float2*)&s_h1[h1rb][e][2 * j2];
          float2 uB = *(const float2*)&s_h1[h1rb][e + 32][2 * j2];
          h1A[2 * j2] = uA.x; h1A[2 * j2 + 1] = uA.y;
          h1B[2 * j2] = uB.x; h1B[2 * j2 + 1] = uB.y;
        }
        float* dstA = &s_h1[h0b][e][u0];
        float* dstB = &s_h1[h0b][e + 32][u0];
        l1_chunk2(s_w, u0, hpA, hpB, h1A, h1B, cA, cB, dstA, dstB,
                  (double)w0.x, (double)w0.y,
                  (double)w1.x, (double)w1.y,
                  (double)w2.x, (double)w2.y, lgA, lgB);
      }
    } else {
      if (s >= 1) {
        const int t1 = s - 1;
        const int h0b = t1 & 1;
        const int h1rb = (t1 + 1) & 1;
        const int col = t1 * HH + u0;  // u0 in {12,16} -> float2 aligned
        float2 w00 = wd2[(0    + col) >> 1];
        float2 w10 = wd2[(4000 + col) >> 1];
        float2 w20 = wd2[(8000 + col) >> 1];
        float2 w01 = wd2[(0    + col + 2) >> 1];
        float2 w11 = wd2[(4000 + col + 2) >> 1];
        float2 w21 = wd2[(8000 + col + 2) >> 1];
        float hp0[HH], h1r[HH];
#pragma unroll
        for (int j2 = 0; j2 < 10; ++j2) {
          float2 vA = *(const float2*)&s_h0[h0b][el][2 * j2];
          float2 uA = *(const float2*)&s_h1[h1rb][el][2 * j2];
          hp0[2 * j2] = vA.x; hp0[2 * j2 + 1] = vA.y;
          h1r[2 * j2] = uA.x; h1r[2 * j2 + 1] = uA.y;
        }
        float* dst = &s_h1[h0b][el][u0];
        l1_smem2(Wih1, Whh1, bih1, bhh1, u0,     hp0, h1r, cA + 0, dst + 0,
                 w00, w10, w20, lgA);
        l1_smem2(Wih1, Whh1, bih1, bhh1, u0 + 2, hp0, h1r, cA + 2, dst + 2,
                 w01, w11, w21, lgB);
      }
    }
    __syncthreads();
  }

  // final states: h(199) in buffer 1 (199&1==1)
  if (isL0) {
#pragma unroll
    for (int u = 0; u < 4; ++u) {
      if (u < nu) {
        out[2 * BB + eg0 * HH + u0 + u] = s_h0[1][e][u0 + u];
        out[2 * BB + eg1 * HH + u0 + u] = s_h0[1][e + 32][u0 + u];
        out[2 * BB + 2 * BB * HH + eg0 * HH + u0 + u] = cA[u];
        out[2 * BB + 2 * BB * HH + eg1 * HH + u0 + u] = cB[u];
      }
    }
  } else if (!isSm) {
#pragma unroll
    for (int u = 0; u < 2; ++u) {
      out[2 * BB + BB * HH + eg0 * HH + u0 + u] = s_h1[1][e][u0 + u];
      out[2 * BB + BB * HH + eg1 * HH + u0 + u] = s_h1[1][e + 32][u0 + u];
      out[2 * BB + 2 * BB * HH + BB * HH + eg0 * HH + u0 + u] = cA[u];
      out[2 * BB + 2 * BB * HH + BB * HH + eg1 * HH + u0 + u] = cB[u];
    }
    const int k = (wv - 3) * 2 + hf;  // units 2k,2k+1 (0..11)
    s_logit[k][e][0] = lgA[0];
    s_logit[k][e][1] = lgA[1];
    s_logit[k][e][2] = lgA[2];
    s_logit[k][e + 32][0] = lgB[0];
    s_logit[k][e + 32][1] = lgB[1];
    s_logit[k][e + 32][2] = lgB[2];
  } else {
#pragma unroll
    for (int u = 0; u < 4; ++u) {
      out[2 * BB + BB * HH + egl * HH + u0 + u] = s_h1[1][el][u0 + u];
      out[2 * BB + 2 * BB * HH + BB * HH + egl * HH + u0 + u] = cA[u];
    }
    const int k0 = 6 + (wv - 6) * 2;  // units 12-13 -> 6, ..., 18-19 -> 9
    s_logit[k0][el][0] = lgA[0];
    s_logit[k0][el][1] = lgA[1];
    s_logit[k0][el][2] = lgA[2];
    s_logit[k0 + 1][el][0] = lgB[0];
    s_logit[k0 + 1][el][1] = lgB[1];
    s_logit[k0 + 1][el][2] = lgB[2];
  }
  __syncthreads();

  if (wv == 0) {
    const int ed = lane;                 // 64 lanes, one element each
    const int egd = blockIdx.x * EPB + ed;
    double l[3];
#pragma unroll
    for (int a = 0; a < 3; ++a) {
      double v = g_bd[a];
#pragma unroll
      for (int k = 0; k < 10; ++k) v += s_logit[k][ed][a];
      l[a] = v;
    }

    // partitionable 32-bit stream: hi^lo of threefry2x32(key, (0, flat_idx))
    int act = 0;
    double vbest = -1.0e300;
#pragma unroll
    for (int a = 0; a < 3; ++a) {
      unsigned idx = 3u * (unsigned)egd + (unsigned)a;
      unsigned p0, p1;
      tf2x32(0u, idx, &p0, &p1);
      double g = bits2gumbel(p0 ^ p1);
      double v = l[a] + g;
      if (v > vbest) { vbest = v; act = a; }  // strict >: first max (argmax)
    }
    double m = fmax(l[0], fmax(l[1], l[2]));
    double se = exp(l[0] - m) + exp(l[1] - m) + exp(l[2] - m);
    double lp = (l[act] - m) - log(se);
    out[egd] = (float)act;
    out[BB + egd] = (float)lp;
  }
}

extern "C" void kernel_launch(void* const* d_in, const int* in_sizes, int n_in,
                              void* d_out, int out_size, void* d_ws, size_t ws_size,
                              hipStream_t stream) {
  prep_kernel<<<dim3(1), dim3(64), 0, stream>>>((const float*)d_in[12]);
  lstm_wave_kernel<<<dim3(BB / EPB), dim3(512), 0, stream>>>(
      (const float*)d_in[0], (const float*)d_in[1], (const float*)d_in[2],
      (const float*)d_in[3], (const float*)d_in[4],
      (const float*)d_in[5], (const float*)d_in[6],
      (const float*)d_in[7], (const float*)d_in[8],
      (const float*)d_in[9], (const float*)d_in[10],
      (const float*)d_in[11], (float*)d_out);
}

// Round 14
// 711.069 us; speedup vs baseline: 1.6616x; 1.4765x over previous
//
#include <hip/hip_runtime.h>
#include <math.h>

#define TT 200
#define BB 16384
#define HH 20
#define EPB 64   // elements per block; each lane handles 2 (e and e+32)

// s_w layout (f32 element offsets), gate-transposed for v_pk_fma_f32:
// W*pk: [unit][j][gate] ; biases: [unit][gate]
#define OWI0P 0      // 160   W_ih0 pk [20][2][4]
#define OWH0P 160    // 1600  W_hh0 pk [20][20][4]
#define OB0P  1760   // 80    (b_ih0+b_hh0) pk [20][4]
#define OWI1P 1840   // 1600  W_ih1 pk [20][20][4]
#define OWH1P 3440   // 1600  W_hh1 pk [20][20][4]
#define OB1P  5040   // 80    (b_ih1+b_hh1) pk [20][4]
#define SWN   5120

typedef float v2f __attribute__((ext_vector_type(2)));

__device__ double g_bd[3];   // b_dec in f64

// ---------- JAX threefry2x32, key = jax.random.key(42) = [0, 42] ----------
__device__ __forceinline__ void tf2x32(unsigned x0, unsigned x1,
                                       unsigned* o0, unsigned* o1) {
  const unsigned ks0 = 0u, ks1 = 42u;
  const unsigned ks2 = ks0 ^ ks1 ^ 0x1BD11BDAu;
  x0 += ks0; x1 += ks1;
#define ROTL_(v, d) (((v) << (d)) | ((v) >> (32 - (d))))
#define RND_(r) { x0 += x1; x1 = ROTL_(x1, r); x1 ^= x0; }
  RND_(13) RND_(15) RND_(26) RND_(6)
  x0 += ks1; x1 += ks2 + 1u;
  RND_(17) RND_(29) RND_(16) RND_(24)
  x0 += ks2; x1 += ks0 + 2u;
  RND_(13) RND_(15) RND_(26) RND_(6)
  x0 += ks0; x1 += ks1 + 3u;
  RND_(17) RND_(29) RND_(16) RND_(24)
  x0 += ks1; x1 += ks2 + 4u;
  RND_(13) RND_(15) RND_(26) RND_(6)
  x0 += ks2; x1 += ks0 + 5u;
  *o0 = x0; *o1 = x1;
#undef RND_
#undef ROTL_
}

// uniform bits -> gumbel sample (f32 bit manipulation exact; logs in f64)
__device__ __forceinline__ double bits2gumbel(unsigned bits) {
  float f = __uint_as_float((bits >> 9) | 0x3F800000u) - 1.0f;
  float uf = (f > 0.0f) ? f : 1.17549435e-38f;  // max(tiny, f) semantics
  return -log(-log((double)uf));
}

// ---------- f32 activations (HW exp + HW rcp, no clamp / no NR) ----------
__device__ __forceinline__ float sigm_f(float x) {
  float e = __expf(-x);
  return __builtin_amdgcn_rcpf(1.0f + e);
}
__device__ __forceinline__ float tanh_f(float x) {
  float e = __expf(2.0f * x);
  return 1.0f - 2.0f * __builtin_amdgcn_rcpf(1.0f + e);
}

__global__ void prep_kernel(const float* __restrict__ b_dec) {
  int i = threadIdx.x;
  if (i < 3) g_bd[i] = (double)b_dec[i];
}

// layer-0 chunk, 2 elements per lane (r9): each weight ds_read_b128 feeds
// 4 v_pk_fma_f32. Bias comes from registers (bs, preloaded once).
// Per-gate FMA order: bias, ih j asc, hh j asc — identical to r9.
template <int NC>
__device__ __forceinline__ void l0_chunk(const float* __restrict__ sw, int u0,
                                         const float4* __restrict__ bs,
                                         float x0a, float x1a,
                                         float x0b, float x1b,
                                         const float* hpA, const float* hpB,
                                         float* cA, float* cB,
                                         float* dstA, float* dstB) {
  v2f a01[NC], a23[NC], b01[NC], b23[NC];
#pragma unroll
  for (int u = 0; u < NC; ++u) {
    float4 b = bs[u];
    a01[u] = (v2f){b.x, b.y}; a23[u] = (v2f){b.z, b.w};
    b01[u] = (v2f){b.x, b.y}; b23[u] = (v2f){b.z, b.w};
  }
#pragma unroll
  for (int u = 0; u < NC; ++u) {
    float4 wa = *(const float4*)&sw[OWI0P + (u0 + u) * 8 + 0];
    float4 wb = *(const float4*)&sw[OWI0P + (u0 + u) * 8 + 4];
    a01[u] = __builtin_elementwise_fma((v2f){wa.x, wa.y}, (v2f){x0a, x0a}, a01[u]);
    a23[u] = __builtin_elementwise_fma((v2f){wa.z, wa.w}, (v2f){x0a, x0a}, a23[u]);
    b01[u] = __builtin_elementwise_fma((v2f){wa.x, wa.y}, (v2f){x0b, x0b}, b01[u]);
    b23[u] = __builtin_elementwise_fma((v2f){wa.z, wa.w}, (v2f){x0b, x0b}, b23[u]);
    a01[u] = __builtin_elementwise_fma((v2f){wb.x, wb.y}, (v2f){x1a, x1a}, a01[u]);
    a23[u] = __builtin_elementwise_fma((v2f){wb.z, wb.w}, (v2f){x1a, x1a}, a23[u]);
    b01[u] = __builtin_elementwise_fma((v2f){wb.x, wb.y}, (v2f){x1b, x1b}, b01[u]);
    b23[u] = __builtin_elementwise_fma((v2f){wb.z, wb.w}, (v2f){x1b, x1b}, b23[u]);
  }
#pragma unroll
  for (int j = 0; j < HH; ++j) {
    v2f ha = (v2f){hpA[j], hpA[j]};
    v2f hb = (v2f){hpB[j], hpB[j]};
#pragma unroll
    for (int u = 0; u < NC; ++u) {
      float4 w = *(const float4*)&sw[OWH0P + ((u0 + u) * HH + j) * 4];
      a01[u] = __builtin_elementwise_fma((v2f){w.x, w.y}, ha, a01[u]);
      a23[u] = __builtin_elementwise_fma((v2f){w.z, w.w}, ha, a23[u]);
      b01[u] = __builtin_elementwise_fma((v2f){w.x, w.y}, hb, b01[u]);
      b23[u] = __builtin_elementwise_fma((v2f){w.z, w.w}, hb, b23[u]);
    }
  }
#pragma unroll
  for (int u = 0; u < NC; ++u) {
    { float si = sigm_f(a01[u].x), sf = sigm_f(a01[u].y);
      float tg = tanh_f(a23[u].x), so = sigm_f(a23[u].y);
      float c = fmaf(sf, cA[u], si * tg);
      cA[u] = c; dstA[u] = so * tanh_f(c); }
    { float si = sigm_f(b01[u].x), sf = sigm_f(b01[u].y);
      float tg = tanh_f(b23[u].x), so = sigm_f(b23[u].y);
      float c = fmaf(sf, cB[u], si * tg);
      cB[u] = c; dstB[u] = so * tanh_f(c); }
  }
}

// layer-1 chunk, 2 units x 2 elements; LDS weights; bias from registers.
// Decoder accumulation in f64 (W_dec cols shared by both elements).
__device__ __forceinline__ void l1_chunk2(const float* __restrict__ sw, int u0,
                                          const float4* __restrict__ bs,
                                          const float* hpA, const float* hpB,
                                          const float* h1A, const float* h1B,
                                          float* cA, float* cB,
                                          float* dstA, float* dstB,
                                          double wd00, double wd01,
                                          double wd10, double wd11,
                                          double wd20, double wd21,
                                          double* lgA, double* lgB) {
  v2f a01[2], a23[2], b01[2], b23[2];
#pragma unroll
  for (int u = 0; u < 2; ++u) {
    float4 b = bs[u];
    a01[u] = (v2f){b.x, b.y}; a23[u] = (v2f){b.z, b.w};
    b01[u] = (v2f){b.x, b.y}; b23[u] = (v2f){b.z, b.w};
  }
#pragma unroll
  for (int j = 0; j < HH; ++j) {
    v2f ha = (v2f){hpA[j], hpA[j]};
    v2f hb = (v2f){hpB[j], hpB[j]};
#pragma unroll
    for (int u = 0; u < 2; ++u) {
      float4 w = *(const float4*)&sw[OWI1P + ((u0 + u) * HH + j) * 4];
      a01[u] = __builtin_elementwise_fma((v2f){w.x, w.y}, ha, a01[u]);
      a23[u] = __builtin_elementwise_fma((v2f){w.z, w.w}, ha, a23[u]);
      b01[u] = __builtin_elementwise_fma((v2f){w.x, w.y}, hb, b01[u]);
      b23[u] = __builtin_elementwise_fma((v2f){w.z, w.w}, hb, b23[u]);
    }
  }
#pragma unroll
  for (int j = 0; j < HH; ++j) {
    v2f ha = (v2f){h1A[j], h1A[j]};
    v2f hb = (v2f){h1B[j], h1B[j]};
#pragma unroll
    for (int u = 0; u < 2; ++u) {
      float4 w = *(const float4*)&sw[OWH1P + ((u0 + u) * HH + j) * 4];
      a01[u] = __builtin_elementwise_fma((v2f){w.x, w.y}, ha, a01[u]);
      a23[u] = __builtin_elementwise_fma((v2f){w.z, w.w}, ha, a23[u]);
      b01[u] = __builtin_elementwise_fma((v2f){w.x, w.y}, hb, b01[u]);
      b23[u] = __builtin_elementwise_fma((v2f){w.z, w.w}, hb, b23[u]);
    }
  }
#pragma unroll
  for (int u = 0; u < 2; ++u) {
    { float si = sigm_f(a01[u].x), sf = sigm_f(a01[u].y);
      float tg = tanh_f(a23[u].x), so = sigm_f(a23[u].y);
      float c = fmaf(sf, cA[u], si * tg);
      cA[u] = c;
      float h = so * tanh_f(c);
      dstA[u] = h;
      double hd = (double)h;
      if (u == 0) { lgA[0] = fma(wd00, hd, lgA[0]); lgA[1] = fma(wd10, hd, lgA[1]); lgA[2] = fma(wd20, hd, lgA[2]); }
      else        { lgA[0] = fma(wd01, hd, lgA[0]); lgA[1] = fma(wd11, hd, lgA[1]); lgA[2] = fma(wd21, hd, lgA[2]); } }
    { float si = sigm_f(b01[u].x), sf = sigm_f(b01[u].y);
      float tg = tanh_f(b23[u].x), so = sigm_f(b23[u].y);
      float c = fmaf(sf, cB[u], si * tg);
      cB[u] = c;
      float h = so * tanh_f(c);
      dstB[u] = h;
      double hd = (double)h;
      if (u == 0) { lgB[0] = fma(wd00, hd, lgB[0]); lgB[1] = fma(wd10, hd, lgB[1]); lgB[2] = fma(wd20, hd, lgB[2]); }
      else        { lgB[0] = fma(wd01, hd, lgB[0]); lgB[1] = fma(wd11, hd, lgB[1]); lgB[2] = fma(wd21, hd, lgB[2]); } }
  }
}

// 8 waves / 64 elements / 256 blocks (1 block/CU). Lane handles elements
// e=lane&31 and e+32, unit-chunk by (wave, half=lane>>5): wave 0 = L0 {4,4};
// waves 1-2 = L0 {3,3}; waves 3-7 = L1 {2,2}, pipelined one step behind.
// Each weight ds_read_b128 is amortized over 2 elements; biases preloaded
// into registers (20 fewer broadcast b128 per CU-phase).
__global__ __launch_bounds__(512, 2) void lstm_wave_kernel(
    const float* __restrict__ x,      // [T,B,2]
    const float* __restrict__ h0_in,  // [2,B,20]
    const float* __restrict__ c0_in,  // [2,B,20]
    const float* __restrict__ Wih0,   // [80,2]
    const float* __restrict__ Whh0,   // [80,20]
    const float* __restrict__ bih0,   // [80]
    const float* __restrict__ bhh0,   // [80]
    const float* __restrict__ Wih1,   // [80,20]
    const float* __restrict__ Whh1,   // [80,20]
    const float* __restrict__ bih1,   // [80]
    const float* __restrict__ bhh1,   // [80]
    const float* __restrict__ Wdec_f, // [3,4000]
    float* __restrict__ out) {
  __shared__ float s_h0[2][EPB][22];   // stride 22 dwords
  __shared__ float s_h1[2][EPB][22];
  __shared__ double s_logit[10][EPB][3];
  __shared__ __align__(16) float s_w[SWN];  // gate-transposed weights

  const int tid = threadIdx.x;
  const int lane = tid & 63;
  const int wv = __builtin_amdgcn_readfirstlane((int)(tid >> 6));
  const int e = lane & 31;
  const int hf = lane >> 5;
  const int eg0 = blockIdx.x * EPB + e;
  const int eg1 = eg0 + 32;

  // stage gate-transposed weights/biases into LDS (one-time)
  for (int i = tid; i < SWN; i += 512) {
    float v;
    if (i < OWH0P) {                     // ih0: i = (u*2+j)*4+g
      int g = i & 3, t = i >> 2, j = t & 1, u = t >> 1;
      v = Wih0[(g * 20 + u) * 2 + j];
    } else if (i < OB0P) {               // hh0: k = (u*20+j)*4+g
      int k = i - OWH0P, g = k & 3, t = k >> 2, j = t % 20, u = t / 20;
      v = Whh0[(g * 20 + u) * 20 + j];
    } else if (i < OWI1P) {              // b0: k = u*4+g
      int k = i - OB0P, g = k & 3, u = k >> 2;
      v = bih0[g * 20 + u] + bhh0[g * 20 + u];
    } else if (i < OWH1P) {              // ih1
      int k = i - OWI1P, g = k & 3, t = k >> 2, j = t % 20, u = t / 20;
      v = Wih1[(g * 20 + u) * 20 + j];
    } else if (i < OB1P) {               // hh1
      int k = i - OWH1P, g = k & 3, t = k >> 2, j = t % 20, u = t / 20;
      v = Whh1[(g * 20 + u) * 20 + j];
    } else {                             // b1
      int k = i - OB1P, g = k & 3, u = k >> 2;
      v = bih1[g * 20 + u] + bhh1[g * 20 + u];
    }
    s_w[i] = v;
  }

  const bool isL0 = (wv < 3);
  int u0, nu;  // u0 is PER-LANE (half-dependent); nu is wave-uniform
  if (isL0) {
    if (wv == 0) { u0 = hf * 4;               nu = 4; }
    else         { u0 = 8 + (wv - 1) * 6 + hf * 3; nu = 3; }
  } else {
    u0 = (wv - 3) * 4 + hf * 2; nu = 2;
  }

  float cA[4], cB[4];
  double lgA[3] = {0.0, 0.0, 0.0};
  double lgB[3] = {0.0, 0.0, 0.0};

  // init: h(-1) into buffer 1 (phases 0/1 read it there)
  {
    const int l = isL0 ? 0 : 1;
#pragma unroll
    for (int u = 0; u < 4; ++u) {
      if (u < nu) {
        cA[u] = c0_in[l * BB * HH + eg0 * HH + u0 + u];
        cB[u] = c0_in[l * BB * HH + eg1 * HH + u0 + u];
        float hA = h0_in[l * BB * HH + eg0 * HH + u0 + u];
        float hB = h0_in[l * BB * HH + eg1 * HH + u0 + u];
        if (isL0) { s_h0[1][e][u0 + u] = hA; s_h0[1][e + 32][u0 + u] = hB; }
        else      { s_h1[1][e][u0 + u] = hA; s_h1[1][e + 32][u0 + u] = hB; }
      }
    }
  }
  __syncthreads();

  // preload bias float4s into registers (one-time; <=16 VGPRs on L0 path)
  float4 bs[4];
#pragma unroll
  for (int u = 0; u < 4; ++u) {
    if (u < nu) {
      bs[u] = isL0 ? *(const float4*)&s_w[OB0P + (u0 + u) * 4]
                   : *(const float4*)&s_w[OB1P + (u0 + u) * 4];
    }
  }

  const float2* x2 = (const float2*)x;
  const float2* wd2 = (const float2*)Wdec_f;

  // x prefetch registers: hold x(t) one full phase ahead for both elements.
  float2 xvA_cur, xvB_cur;
  if (isL0) { xvA_cur = x2[0 * BB + eg0]; xvB_cur = x2[0 * BB + eg1]; }

  // phase s: L0 computes t=s (s<200): reads h0 buf (s+1)&1, writes s&1.
  //          L1 computes t1=s-1 (s>=1): h0(t1) from t1&1, own h1(t1-1) from
  //          (t1+1)&1, writes h1(t1) -> t1&1.
  for (int s = 0; s <= TT; ++s) {
    if (isL0) {
      if (s < TT) {
        const int rb = (s + 1) & 1;
        const int wb = s & 1;
        float2 xvA = xvA_cur, xvB = xvB_cur;
        if (s + 1 < TT) {
          xvA_cur = x2[(s + 1) * BB + eg0];
          xvB_cur = x2[(s + 1) * BB + eg1];
        }
        float hpA[HH], hpB[HH];
#pragma unroll
        for (int j2 = 0; j2 < 10; ++j2) {
          float2 vA = *(const float2*)&s_h0[rb][e][2 * j2];
          float2 vB = *(const float2*)&s_h0[rb][e + 32][2 * j2];
          hpA[2 * j2] = vA.x; hpA[2 * j2 + 1] = vA.y;
          hpB[2 * j2] = vB.x; hpB[2 * j2 + 1] = vB.y;
        }
        float* dstA = &s_h0[wb][e][u0];
        float* dstB = &s_h0[wb][e + 32][u0];
        if (wv == 0) l0_chunk<4>(s_w, u0, bs, xvA.x, xvA.y, xvB.x, xvB.y, hpA, hpB, cA, cB, dstA, dstB);
        else         l0_chunk<3>(s_w, u0, bs, xvA.x, xvA.y, xvB.x, xvB.y, hpA, hpB, cA, cB, dstA, dstB);
      }
    } else {
      if (s >= 1) {
        const int t1 = s - 1;
        const int h0b = t1 & 1;
        const int h1rb = (t1 + 1) & 1;
        // W_dec cols for this step (shared by both elements): f32 global
        // loads (in-order vmcnt), issued here, consumed at tail -> hidden.
        const int col = t1 * HH + u0;  // u0 even -> float2 aligned
        float2 w0 = wd2[(0    + col) >> 1];
        float2 w1 = wd2[(4000 + col) >> 1];
        float2 w2 = wd2[(8000 + col) >> 1];
        float hpA[HH], hpB[HH], h1A[HH], h1B[HH];
#pragma unroll
        for (int j2 = 0; j2 < 10; ++j2) {
          float2 vA = *(const float2*)&s_h0[h0b][e][2 * j2];
          float2 vB = *(const float2*)&s_h0[h0b][e + 32][2 * j2];
          hpA[2 * j2] = vA.x; hpA[2 * j2 + 1] = vA.y;
          hpB[2 * j2] = vB.x; hpB[2 * j2 + 1] = vB.y;
          float2 uA = *(const float2*)&s_h1[h1rb][e][2 * j2];
          float2 uB = *(const float2*)&s_h1[h1rb][e + 32][2 * j2];
          h1A[2 * j2] = uA.x; h1A[2 * j2 + 1] = uA.y;
          h1B[2 * j2] = uB.x; h1B[2 * j2 + 1] = uB.y;
        }
        float* dstA = &s_h1[h0b][e][u0];
        float* dstB = &s_h1[h0b][e + 32][u0];
        l1_chunk2(s_w, u0, bs, hpA, hpB, h1A, h1B, cA, cB, dstA, dstB,
                  (double)w0.x, (double)w0.y,
                  (double)w1.x, (double)w1.y,
                  (double)w2.x, (double)w2.y, lgA, lgB);
      }
    }
    __syncthreads();
  }

  // final states: h(199) in buffer 1 (199&1==1)
  {
    const int l = isL0 ? 0 : 1;
#pragma unroll
    for (int u = 0; u < 4; ++u) {
      if (u < nu) {
        float hA = isL0 ? s_h0[1][e][u0 + u] : s_h1[1][e][u0 + u];
        float hB = isL0 ? s_h0[1][e + 32][u0 + u] : s_h1[1][e + 32][u0 + u];
        out[2 * BB + l * BB * HH + eg0 * HH + u0 + u] = hA;
        out[2 * BB + l * BB * HH + eg1 * HH + u0 + u] = hB;
        out[2 * BB + 2 * BB * HH + l * BB * HH + eg0 * HH + u0 + u] = cA[u];
        out[2 * BB + 2 * BB * HH + l * BB * HH + eg1 * HH + u0 + u] = cB[u];
      }
    }
  }

  if (!isL0) {
    const int k = (wv - 3) * 2 + hf;  // chunk order matches r9
    s_logit[k][e][0] = lgA[0];
    s_logit[k][e][1] = lgA[1];
    s_logit[k][e][2] = lgA[2];
    s_logit[k][e + 32][0] = lgB[0];
    s_logit[k][e + 32][1] = lgB[1];
    s_logit[k][e + 32][2] = lgB[2];
  }
  __syncthreads();

  if (wv == 0) {
    const int ed = lane;                 // 64 lanes, one element each
    const int egd = blockIdx.x * EPB + ed;
    double l[3];
#pragma unroll
    for (int a = 0; a < 3; ++a) {
      double v = g_bd[a];
#pragma unroll
      for (int k = 0; k < 10; ++k) v += s_logit[k][ed][a];
      l[a] = v;
    }

    // partitionable 32-bit stream: hi^lo of threefry2x32(key, (0, flat_idx))
    int act = 0;
    double vbest = -1.0e300;
#pragma unroll
    for (int a = 0; a < 3; ++a) {
      unsigned idx = 3u * (unsigned)egd + (unsigned)a;
      unsigned p0, p1;
      tf2x32(0u, idx, &p0, &p1);
      double g = bits2gumbel(p0 ^ p1);
      double v = l[a] + g;
      if (v > vbest) { vbest = v; act = a; }  // strict >: first max (argmax)
    }
    double m = fmax(l[0], fmax(l[1], l[2]));
    double se = exp(l[0] - m) + exp(l[1] - m) + exp(l[2] - m);
    double lp = (l[act] - m) - log(se);
    out[egd] = (float)act;
    out[BB + egd] = (float)lp;
  }
}

extern "C" void kernel_launch(void* const* d_in, const int* in_sizes, int n_in,
                              void* d_out, int out_size, void* d_ws, size_t ws_size,
                              hipStream_t stream) {
  prep_kernel<<<dim3(1), dim3(64), 0, stream>>>((const float*)d_in[12]);
  lstm_wave_kernel<<<dim3(BB / EPB), dim3(512), 0, stream>>>(
      (const float*)d_in[0], (const float*)d_in[1], (const float*)d_in[2],
      (const float*)d_in[3], (const float*)d_in[4],
      (const float*)d_in[5], (const float*)d_in[6],
      (const float*)d_in[7], (const float*)d_in[8],
      (const float*)d_in[9], (const float*)d_in[10],
      (const float*)d_in[11], (float*)d_out);
}